// Round 1
// baseline (209.276 us; speedup 1.0000x reference)
//
#include <hip/hip_runtime.h>
#include <hip/hip_bf16.h>
#include <math.h>

// Problem constants (from reference)
#define B_N   256
#define EMB_N 512
#define CLS_N 20000
#define PI_F  3.14159265f
// f = 1/(1+LAMB), LAMB = 1500/1.1  ->  f = 1.1/1501.1
#define F_CONST ((float)(1.1 / 1501.1))

// ---------------- Kernel A: per-row prep ----------------
// For each b: xlen, gather Wg[b][:] = W[:, y[b]], ||W_yb||, target cos, margin value.
__global__ __launch_bounds__(256) void prep_kernel(
    const float* __restrict__ emb, const int* __restrict__ y,
    const float* __restrict__ W,
    float* __restrict__ Wg, float* __restrict__ xlen_a,
    float* __restrict__ inv_xlen_a, float* __restrict__ inv_wny_a,
    float* __restrict__ mod_val_a)
{
    const int b = blockIdx.x;
    const int t = threadIdx.x;
    const int yb = y[b];
    const float* erow = emb + (size_t)b * EMB_N;
    float se = 0.f, sw = 0.f, dt = 0.f;
    for (int e = t; e < EMB_N; e += 256) {
        float ev = erow[e];
        float wv = W[(size_t)e * CLS_N + yb];
        Wg[(size_t)b * EMB_N + e] = wv;
        se += ev * ev; sw += wv * wv; dt += ev * wv;
    }
    __shared__ float r0[256], r1[256], r2[256];
    r0[t] = se; r1[t] = sw; r2[t] = dt;
    __syncthreads();
    for (int s = 128; s > 0; s >>= 1) {
        if (t < s) { r0[t] += r0[t + s]; r1[t] += r1[t + s]; r2[t] += r2[t + s]; }
        __syncthreads();
    }
    if (t == 0) {
        float xlen = sqrtf(r0[0]);
        float wn   = sqrtf(r1[0]);
        float inv_x = 1.f / xlen;
        float inv_w = 1.f / wn;
        float cos_t = r2[0] * inv_w * inv_x;
        cos_t = fminf(1.f, fmaxf(-1.f, cos_t));
        float c2 = cos_t * cos_t;
        float cos_m = 8.f * c2 * c2 - 8.f * c2 + 1.f;
        float theta = acosf(cos_t);
        float k = floorf(4.f * theta / PI_F);
        float sgn = 1.f - 2.f * fmodf(k, 2.f);
        float phi = sgn * cos_m - 2.f * k;
        float cos_s = cos_t * xlen;
        float phi_s = phi * xlen;
        xlen_a[b] = xlen;
        inv_xlen_a[b] = inv_x;
        inv_wny_a[b] = inv_w;
        mod_val_a[b] = cos_s + F_CONST * (phi_s - cos_s);
    }
}

// ---------------- Kernel B: column inverse norms of W ----------------
__global__ __launch_bounds__(256) void colnorm_kernel(
    const float* __restrict__ W, float* __restrict__ inv_wnorm)
{
    int c = blockIdx.x * 256 + threadIdx.x;
    if (c >= CLS_N) return;
    float s = 0.f;
    for (int e = 0; e < EMB_N; ++e) {
        float v = W[(size_t)e * CLS_N + c];
        s += v * v;
    }
    inv_wnorm[c] = 1.f / sqrtf(s);
}

// ---------------- Kernel C: fused double GEMM + epilogue ----------------
// D1[b][c] = emb[b] . W[:,c]   -> logits (cos_s)
// D2[b][c] = Wg[b]  . W[:,c]   -> MHE inter term accumulation
constexpr int BM = 64, BN = 64, BK = 16, TM = 4, TN = 4;

__global__ __launch_bounds__(256) void gemm_kernel(
    const float* __restrict__ emb, const float* __restrict__ Wg,
    const float* __restrict__ W, const int* __restrict__ y,
    const float* __restrict__ xlen_a, const float* __restrict__ inv_xlen_a,
    const float* __restrict__ inv_wny_a, const float* __restrict__ inv_wnorm,
    float* __restrict__ logits, float* __restrict__ inter_sum)
{
    __shared__ float As[BK][BM + 4];
    __shared__ float Gs[BK][BM + 4];
    __shared__ float Bs[BK][BN];

    const int t  = threadIdx.x;
    const int tx = t & 15;
    const int ty = t >> 4;
    const int n0 = blockIdx.x * BN;
    const int m0 = blockIdx.y * BM;

    // A/G load mapping: row m0 + (t>>2), k-quad (t&3)*4
    const int am = t >> 2;
    const int ak = (t & 3) * 4;
    // B load mapping: k row t>>4, col quad (t&15)*4
    const int bk = t >> 4;
    const int bn = (t & 15) * 4;

    float acc1[TM][TN] = {{0.f}};
    float acc2[TM][TN] = {{0.f}};

    for (int kt = 0; kt < EMB_N; kt += BK) {
        float4 av = *reinterpret_cast<const float4*>(&emb[(size_t)(m0 + am) * EMB_N + kt + ak]);
        float4 gv = *reinterpret_cast<const float4*>(&Wg [(size_t)(m0 + am) * EMB_N + kt + ak]);
        As[ak + 0][am] = av.x; As[ak + 1][am] = av.y; As[ak + 2][am] = av.z; As[ak + 3][am] = av.w;
        Gs[ak + 0][am] = gv.x; Gs[ak + 1][am] = gv.y; Gs[ak + 2][am] = gv.z; Gs[ak + 3][am] = gv.w;

        int col = n0 + bn;
        float4 bv;
        if (col + 3 < CLS_N) {
            bv = *reinterpret_cast<const float4*>(&W[(size_t)(kt + bk) * CLS_N + col]);
        } else {
            bv.x = (col + 0 < CLS_N) ? W[(size_t)(kt + bk) * CLS_N + col + 0] : 0.f;
            bv.y = (col + 1 < CLS_N) ? W[(size_t)(kt + bk) * CLS_N + col + 1] : 0.f;
            bv.z = (col + 2 < CLS_N) ? W[(size_t)(kt + bk) * CLS_N + col + 2] : 0.f;
            bv.w = (col + 3 < CLS_N) ? W[(size_t)(kt + bk) * CLS_N + col + 3] : 0.f;
        }
        *reinterpret_cast<float4*>(&Bs[bk][bn]) = bv;
        __syncthreads();

        #pragma unroll
        for (int k = 0; k < BK; ++k) {
            float a[TM], g[TM], w[TN];
            #pragma unroll
            for (int i = 0; i < TM; ++i) {
                a[i] = As[k][ty * TM + i];
                g[i] = Gs[k][ty * TM + i];
            }
            #pragma unroll
            for (int j = 0; j < TN; ++j) w[j] = Bs[k][tx * TN + j];
            #pragma unroll
            for (int i = 0; i < TM; ++i)
                #pragma unroll
                for (int j = 0; j < TN; ++j) {
                    acc1[i][j] = fmaf(a[i], w[j], acc1[i][j]);
                    acc2[i][j] = fmaf(g[i], w[j], acc2[i][j]);
                }
        }
        __syncthreads();
    }

    // epilogue
    float interp = 0.f;
    int   ybr[TM];
    float xl[TM], ixl[TM], iwy[TM];
    #pragma unroll
    for (int i = 0; i < TM; ++i) {
        int bb = m0 + ty * TM + i;
        ybr[i] = y[bb];
        xl[i]  = xlen_a[bb];
        ixl[i] = inv_xlen_a[bb];
        iwy[i] = inv_wny_a[bb];
    }
    #pragma unroll
    for (int j = 0; j < TN; ++j) {
        int c = n0 + tx * TN + j;
        if (c >= CLS_N) continue;
        float iwc = inv_wnorm[c];
        #pragma unroll
        for (int i = 0; i < TM; ++i) {
            int bb = m0 + ty * TM + i;
            float cosv = acc1[i][j] * iwc * ixl[i];
            cosv = fminf(1.f, fmaxf(-1.f, cosv));
            logits[(size_t)bb * CLS_N + c] = cosv * xl[i];
            float cww = acc2[i][j] * iwc * iwy[i];
            float d2 = fmaxf(2.f - 2.f * cww, 0.f);
            if (c != ybr[i]) interp += 1.f / d2;
        }
    }
    __shared__ float red[256];
    red[t] = interp;
    __syncthreads();
    for (int s = 128; s > 0; s >>= 1) {
        if (t < s) red[t] += red[t + s];
        __syncthreads();
    }
    if (t == 0) atomicAdd(inter_sum, red[0]);
}

// ---------------- Kernel D: per-row online softmax + argmax ----------------
__global__ __launch_bounds__(256) void row_kernel(
    const float* __restrict__ logits, const int* __restrict__ y,
    const float* __restrict__ mod_val_a,
    float* __restrict__ ce_sum, float* __restrict__ acc_sum)
{
    const int b = blockIdx.x;
    const int t = threadIdx.x;
    const int yb = y[b];
    const float* row = logits + (size_t)b * CLS_N;
    const float mv = mod_val_a[b];

    float m = -INFINITY, s = 0.f;
    float vmax = -INFINITY; int vidx = 0;
    for (int c = t; c < CLS_N; c += 256) {
        float v = row[c];
        float adj = (c == yb) ? mv : v;
        float mn = fmaxf(m, adj);
        s = s * __expf(m - mn) + __expf(adj - mn);
        m = mn;
        if (v > vmax) { vmax = v; vidx = c; }
    }
    __shared__ float sm[256], ss[256], sv[256];
    __shared__ int   si[256];
    sm[t] = m; ss[t] = s; sv[t] = vmax; si[t] = vidx;
    __syncthreads();
    for (int st = 128; st > 0; st >>= 1) {
        if (t < st) {
            float m2 = sm[t + st], s2 = ss[t + st];
            float mn = fmaxf(sm[t], m2);
            ss[t] = ss[t] * __expf(sm[t] - mn) + s2 * __expf(m2 - mn);
            sm[t] = mn;
            float v2 = sv[t + st]; int i2 = si[t + st];
            if (v2 > sv[t] || (v2 == sv[t] && i2 < si[t])) { sv[t] = v2; si[t] = i2; }
        }
        __syncthreads();
    }
    if (t == 0) {
        float lse = sm[0] + logf(ss[0]);
        float logpt = mv - lse;
        atomicAdd(ce_sum, -logpt);
        if (si[0] == yb) atomicAdd(acc_sum, 1.f);
    }
}

// ---------------- Kernel E: finalize scalars ----------------
__global__ void finalize_kernel(const float* __restrict__ accums, float* __restrict__ out)
{
    float ce    = accums[0] / (float)B_N;
    float acc   = accums[1] / (float)B_N;
    float inter = accums[2] / (float)((double)B_N * (CLS_N - 1));
    out[0] = ce + 0.01f * inter;
    out[(size_t)1 + (size_t)B_N * CLS_N + 0] = acc;
    out[(size_t)1 + (size_t)B_N * CLS_N + 1] = inter;
}

extern "C" void kernel_launch(void* const* d_in, const int* in_sizes, int n_in,
                              void* d_out, int out_size, void* d_ws, size_t ws_size,
                              hipStream_t stream) {
    const float* emb = (const float*)d_in[0];
    const int*   y   = (const int*)d_in[1];
    const float* W   = (const float*)d_in[2];
    float* out = (float*)d_out;
    float* logits = out + 1;   // [loss, logits(256x20000), acc, inter]

    float* ws = (float*)d_ws;
    float* Wg         = ws;              // 131072 floats
    float* inv_wnorm  = ws + 131072;     // 20032 (padded)
    float* xlen_a     = ws + 151104;     // 256
    float* inv_xlen_a = ws + 151360;     // 256
    float* inv_wny_a  = ws + 151616;     // 256
    float* mod_val_a  = ws + 151872;     // 256
    float* accums     = ws + 152128;     // [ce_sum, acc_sum, inter_sum]

    hipMemsetAsync(accums, 0, 3 * sizeof(float), stream);

    prep_kernel<<<B_N, 256, 0, stream>>>(emb, y, W, Wg, xlen_a, inv_xlen_a, inv_wny_a, mod_val_a);
    colnorm_kernel<<<(CLS_N + 255) / 256, 256, 0, stream>>>(W, inv_wnorm);

    dim3 ggrid((CLS_N + BN - 1) / BN, B_N / BM);
    gemm_kernel<<<ggrid, 256, 0, stream>>>(emb, Wg, W, y, xlen_a, inv_xlen_a,
                                           inv_wny_a, inv_wnorm, logits,
                                           accums + 2);

    row_kernel<<<B_N, 256, 0, stream>>>(logits, y, mod_val_a, accums + 0, accums + 1);
    finalize_kernel<<<1, 1, 0, stream>>>(accums, out);
}

// Round 2
// 89.319 us; speedup vs baseline: 2.3430x; 2.3430x over previous
//
#include <hip/hip_runtime.h>
#include <hip/hip_bf16.h>
#include <math.h>

#define B_N   256
#define EMB_N 512
#define CLS_N 20000
#define CLS_PAD 20096
#define PI_F  3.14159265f
#define F_CONST ((float)(1.1 / 1501.1))

typedef __bf16 bf16x8 __attribute__((ext_vector_type(8)));
typedef float  f32x4  __attribute__((ext_vector_type(4)));

__device__ __forceinline__ unsigned short f2bf(float f) {
    unsigned u = __float_as_uint(f);
    unsigned r = (u + 0x7FFFu + ((u >> 16) & 1u)) >> 16;  // RNE
    return (unsigned short)r;
}

// ---------------- prep: per-row scalars, gather W[:,y], build bf16 stacked A ----------------
__global__ __launch_bounds__(256) void prep_kernel(
    const float* __restrict__ emb, const int* __restrict__ y,
    const float* __restrict__ W,
    unsigned short* __restrict__ Abf,   // may be null (fallback path)
    float* __restrict__ Wg,             // may be null (fast path)
    float* __restrict__ xlen_a, float* __restrict__ inv_xlen_a,
    float* __restrict__ inv_wny_a, float* __restrict__ mod_val_a)
{
    const int b = blockIdx.x;
    const int t = threadIdx.x;
    const int yb = y[b];
    const float* erow = emb + (size_t)b * EMB_N;
    float se = 0.f, sw = 0.f, dt = 0.f;
    for (int e = t; e < EMB_N; e += 256) {
        float ev = erow[e];
        float wv = W[(size_t)e * CLS_N + yb];
        if (Wg)  Wg[(size_t)b * EMB_N + e] = wv;
        if (Abf) {
            Abf[(size_t)b * EMB_N + e]           = f2bf(ev);
            Abf[(size_t)(B_N + b) * EMB_N + e]   = f2bf(wv);
        }
        se += ev * ev; sw += wv * wv; dt += ev * wv;
    }
    __shared__ float r0[256], r1[256], r2[256];
    r0[t] = se; r1[t] = sw; r2[t] = dt;
    __syncthreads();
    for (int s = 128; s > 0; s >>= 1) {
        if (t < s) { r0[t] += r0[t + s]; r1[t] += r1[t + s]; r2[t] += r2[t + s]; }
        __syncthreads();
    }
    if (t == 0) {
        float xlen = sqrtf(r0[0]);
        float wn   = sqrtf(r1[0]);
        float inv_x = 1.f / xlen;
        float inv_w = 1.f / wn;
        float cos_t = r2[0] * inv_w * inv_x;
        cos_t = fminf(1.f, fmaxf(-1.f, cos_t));
        float c2 = cos_t * cos_t;
        float cos_m = 8.f * c2 * c2 - 8.f * c2 + 1.f;
        float theta = acosf(cos_t);
        float k = floorf(4.f * theta / PI_F);
        float sgn = 1.f - 2.f * fmodf(k, 2.f);
        float phi = sgn * cos_m - 2.f * k;
        float cos_s = cos_t * xlen;
        float phi_s = phi * xlen;
        xlen_a[b] = xlen;
        inv_xlen_a[b] = inv_x;
        inv_wny_a[b] = inv_w;
        mod_val_a[b] = cos_s + F_CONST * (phi_s - cos_s);
    }
}

// ---------------- convertW: W[K][N] fp32 -> Wt[N_pad][K] bf16 (transposed) + colsumsq ----------------
// grid (79, 4): block column-chunk of 256 classes, k-chunk of 128.
__global__ __launch_bounds__(256) void convertW_kernel(
    const float* __restrict__ W, unsigned short* __restrict__ Wt,
    float* __restrict__ colsumsq)
{
    const int c = blockIdx.x * 256 + threadIdx.x;
    const int e0 = blockIdx.y * (EMB_N / 4);
    const bool valid = (c < CLS_N);
    float ssq = 0.f;
    for (int r = 0; r < (EMB_N / 4) / 8; ++r) {
        unsigned short buf[8];
        #pragma unroll
        for (int j = 0; j < 8; ++j) {
            int e = e0 + r * 8 + j;
            float v = valid ? W[(size_t)e * CLS_N + c] : 0.f;
            ssq += v * v;
            buf[j] = f2bf(v);
        }
        if (c < CLS_PAD)
            *reinterpret_cast<uint4*>(Wt + (size_t)c * EMB_N + e0 + r * 8) =
                *reinterpret_cast<const uint4*>(buf);
    }
    if (valid) atomicAdd(&colsumsq[c], ssq);
}

// ---------------- MFMA GEMM: D = [emb; Wg](512x512) x W(512x20000), fused epilogue ----------------
// 128x128 tile, BK=64, 4 waves (2x2), each wave 64x64 = 4x4 frags of 16x16x32 bf16 MFMA.
// LDS rows are 128B -> XOR swizzle byte^=((row&7)<<4) on both write and read (T2).
__global__ __launch_bounds__(256) void mfma_gemm_kernel(
    const unsigned short* __restrict__ Abf, const unsigned short* __restrict__ Wt,
    const float* __restrict__ colsumsq, const int* __restrict__ y,
    const float* __restrict__ xlen_a, const float* __restrict__ inv_xlen_a,
    const float* __restrict__ inv_wny_a,
    float* __restrict__ logits, float* __restrict__ inter_sum)
{
    __shared__ alignas(16) char sA[128 * 64 * 2];
    __shared__ alignas(16) char sB[128 * 64 * 2];
    __shared__ float red[256];

    const int t    = threadIdx.x;
    const int lane = t & 63;
    const int wid  = t >> 6;
    const int wr   = wid >> 1;        // wave row (0..1) -> 64 rows each
    const int wc   = wid & 1;         // wave col (0..1) -> 64 cols each
    const int r16  = lane & 15;
    const int kh   = lane >> 4;       // 0..3
    const int m0   = blockIdx.y * 128;
    const int n0   = blockIdx.x * 128;

    f32x4 acc[4][4] = {};

    const char* Ab = (const char*)Abf;
    const char* Bb = (const char*)Wt;

    for (int kt = 0; kt < EMB_N; kt += 64) {
        #pragma unroll
        for (int r = 0; r < 4; ++r) {
            int idx = r * 256 + t;
            int row = idx >> 3;
            int cb  = (idx & 7) << 4;                 // byte offset within 128B k-slice
            int sw  = (row * 128 + cb) ^ ((row & 7) << 4);
            *reinterpret_cast<uint4*>(sA + sw) =
                *reinterpret_cast<const uint4*>(Ab + (size_t)(m0 + row) * 1024 + kt * 2 + cb);
            *reinterpret_cast<uint4*>(sB + sw) =
                *reinterpret_cast<const uint4*>(Bb + (size_t)(n0 + row) * 1024 + kt * 2 + cb);
        }
        __syncthreads();
        #pragma unroll
        for (int kk = 0; kk < 2; ++kk) {
            bf16x8 af[4], bfr[4];
            #pragma unroll
            for (int mi = 0; mi < 4; ++mi) {
                int row = wr * 64 + mi * 16 + r16;
                int off = (row * 128 + kk * 64 + kh * 16) ^ ((row & 7) << 4);
                af[mi] = *reinterpret_cast<const bf16x8*>(sA + off);
            }
            #pragma unroll
            for (int ni = 0; ni < 4; ++ni) {
                int row = wc * 64 + ni * 16 + r16;
                int off = (row * 128 + kk * 64 + kh * 16) ^ ((row & 7) << 4);
                bfr[ni] = *reinterpret_cast<const bf16x8*>(sB + off);
            }
            #pragma unroll
            for (int mi = 0; mi < 4; ++mi)
                #pragma unroll
                for (int ni = 0; ni < 4; ++ni)
                    acc[mi][ni] = __builtin_amdgcn_mfma_f32_16x16x32_bf16(
                        af[mi], bfr[ni], acc[mi][ni], 0, 0, 0);
        }
        __syncthreads();
    }

    // column constants for this thread (4 ni positions)
    int   cc[4]; float iwc[4];
    #pragma unroll
    for (int ni = 0; ni < 4; ++ni) {
        cc[ni] = n0 + wc * 64 + ni * 16 + r16;
        iwc[ni] = (cc[ni] < CLS_N) ? rsqrtf(colsumsq[cc[ni]]) : 0.f;
    }

    if (m0 < B_N) {
        // logits rows
        #pragma unroll
        for (int mi = 0; mi < 4; ++mi) {
            int mbase = m0 + wr * 64 + mi * 16 + kh * 4;
            float xl[4], ixl[4];
            #pragma unroll
            for (int r = 0; r < 4; ++r) { xl[r] = xlen_a[mbase + r]; ixl[r] = inv_xlen_a[mbase + r]; }
            #pragma unroll
            for (int ni = 0; ni < 4; ++ni) {
                if (cc[ni] >= CLS_N) continue;
                #pragma unroll
                for (int r = 0; r < 4; ++r) {
                    float cosv = acc[mi][ni][r] * iwc[ni] * ixl[r];
                    cosv = fminf(1.f, fmaxf(-1.f, cosv));
                    logits[(size_t)(mbase + r) * CLS_N + cc[ni]] = cosv * xl[r];
                }
            }
        }
    } else {
        // MHE inter rows
        float part = 0.f;
        #pragma unroll
        for (int mi = 0; mi < 4; ++mi) {
            int bbase = (m0 - B_N) + wr * 64 + mi * 16 + kh * 4;
            float iwy[4]; int yy[4];
            #pragma unroll
            for (int r = 0; r < 4; ++r) { iwy[r] = inv_wny_a[bbase + r]; yy[r] = y[bbase + r]; }
            #pragma unroll
            for (int ni = 0; ni < 4; ++ni) {
                if (cc[ni] >= CLS_N) continue;
                #pragma unroll
                for (int r = 0; r < 4; ++r) {
                    float cww = acc[mi][ni][r] * iwc[ni] * iwy[r];
                    float d2 = fmaxf(2.f - 2.f * cww, 0.f);
                    if (cc[ni] != yy[r]) part += 1.f / d2;
                }
            }
        }
        red[t] = part;
        __syncthreads();
        for (int s = 128; s > 0; s >>= 1) {
            if (t < s) red[t] += red[t + s];
            __syncthreads();
        }
        if (t == 0) atomicAdd(inter_sum, red[0]);
    }
}

// ---------------- fallback fp32 SIMT kernels (round-1 path, used only if ws too small) ----------------
__global__ __launch_bounds__(256) void colnorm_kernel(
    const float* __restrict__ W, float* __restrict__ inv_wnorm)
{
    int c = blockIdx.x * 256 + threadIdx.x;
    if (c >= CLS_N) return;
    float s = 0.f;
    for (int e = 0; e < EMB_N; ++e) {
        float v = W[(size_t)e * CLS_N + c];
        s += v * v;
    }
    inv_wnorm[c] = 1.f / sqrtf(s);
}

constexpr int BM = 64, BN = 64, BK = 16, TM = 4, TN = 4;
__global__ __launch_bounds__(256) void gemm_old_kernel(
    const float* __restrict__ emb, const float* __restrict__ Wg,
    const float* __restrict__ W, const int* __restrict__ y,
    const float* __restrict__ xlen_a, const float* __restrict__ inv_xlen_a,
    const float* __restrict__ inv_wny_a, const float* __restrict__ inv_wnorm,
    float* __restrict__ logits, float* __restrict__ inter_sum)
{
    __shared__ float As[BK][BM + 4];
    __shared__ float Gs[BK][BM + 4];
    __shared__ float Bs[BK][BN];
    const int t  = threadIdx.x;
    const int tx = t & 15;
    const int ty = t >> 4;
    const int n0 = blockIdx.x * BN;
    const int m0 = blockIdx.y * BM;
    const int am = t >> 2;
    const int ak = (t & 3) * 4;
    const int bk = t >> 4;
    const int bn = (t & 15) * 4;
    float acc1[TM][TN] = {{0.f}};
    float acc2[TM][TN] = {{0.f}};
    for (int kt = 0; kt < EMB_N; kt += BK) {
        float4 av = *reinterpret_cast<const float4*>(&emb[(size_t)(m0 + am) * EMB_N + kt + ak]);
        float4 gv = *reinterpret_cast<const float4*>(&Wg [(size_t)(m0 + am) * EMB_N + kt + ak]);
        As[ak + 0][am] = av.x; As[ak + 1][am] = av.y; As[ak + 2][am] = av.z; As[ak + 3][am] = av.w;
        Gs[ak + 0][am] = gv.x; Gs[ak + 1][am] = gv.y; Gs[ak + 2][am] = gv.z; Gs[ak + 3][am] = gv.w;
        int col = n0 + bn;
        float4 bv;
        if (col + 3 < CLS_N) {
            bv = *reinterpret_cast<const float4*>(&W[(size_t)(kt + bk) * CLS_N + col]);
        } else {
            bv.x = (col + 0 < CLS_N) ? W[(size_t)(kt + bk) * CLS_N + col + 0] : 0.f;
            bv.y = (col + 1 < CLS_N) ? W[(size_t)(kt + bk) * CLS_N + col + 1] : 0.f;
            bv.z = (col + 2 < CLS_N) ? W[(size_t)(kt + bk) * CLS_N + col + 2] : 0.f;
            bv.w = (col + 3 < CLS_N) ? W[(size_t)(kt + bk) * CLS_N + col + 3] : 0.f;
        }
        *reinterpret_cast<float4*>(&Bs[bk][bn]) = bv;
        __syncthreads();
        #pragma unroll
        for (int k = 0; k < BK; ++k) {
            float a[TM], g[TM], w[TN];
            #pragma unroll
            for (int i = 0; i < TM; ++i) { a[i] = As[k][ty * TM + i]; g[i] = Gs[k][ty * TM + i]; }
            #pragma unroll
            for (int j = 0; j < TN; ++j) w[j] = Bs[k][tx * TN + j];
            #pragma unroll
            for (int i = 0; i < TM; ++i)
                #pragma unroll
                for (int j = 0; j < TN; ++j) {
                    acc1[i][j] = fmaf(a[i], w[j], acc1[i][j]);
                    acc2[i][j] = fmaf(g[i], w[j], acc2[i][j]);
                }
        }
        __syncthreads();
    }
    float interp = 0.f;
    int ybr[TM]; float xl[TM], ixl[TM], iwy[TM];
    #pragma unroll
    for (int i = 0; i < TM; ++i) {
        int bb = m0 + ty * TM + i;
        ybr[i] = y[bb]; xl[i] = xlen_a[bb]; ixl[i] = inv_xlen_a[bb]; iwy[i] = inv_wny_a[bb];
    }
    #pragma unroll
    for (int j = 0; j < TN; ++j) {
        int c = n0 + tx * TN + j;
        if (c >= CLS_N) continue;
        float iwc = inv_wnorm[c];
        #pragma unroll
        for (int i = 0; i < TM; ++i) {
            int bb = m0 + ty * TM + i;
            float cosv = acc1[i][j] * iwc * ixl[i];
            cosv = fminf(1.f, fmaxf(-1.f, cosv));
            logits[(size_t)bb * CLS_N + c] = cosv * xl[i];
            float cww = acc2[i][j] * iwc * iwy[i];
            float d2 = fmaxf(2.f - 2.f * cww, 0.f);
            if (c != ybr[i]) interp += 1.f / d2;
        }
    }
    __shared__ float red[256];
    red[t] = interp;
    __syncthreads();
    for (int s = 128; s > 0; s >>= 1) {
        if (t < s) red[t] += red[t + s];
        __syncthreads();
    }
    if (t == 0) atomicAdd(inter_sum, red[0]);
}

// ---------------- row softmax + argmax (vectorized) ----------------
__global__ __launch_bounds__(256) void row_kernel(
    const float* __restrict__ logits, const int* __restrict__ y,
    const float* __restrict__ mod_val_a,
    float* __restrict__ ce_sum, float* __restrict__ acc_sum)
{
    const int b = blockIdx.x;
    const int t = threadIdx.x;
    const int yb = y[b];
    const float4* row4 = reinterpret_cast<const float4*>(logits + (size_t)b * CLS_N);

    float m = -INFINITY, s = 0.f, vmax = -INFINITY;
    int vidx = 0;
    for (int i = t; i < CLS_N / 4; i += 256) {
        float4 v4 = row4[i];
        float vv[4] = {v4.x, v4.y, v4.z, v4.w};
        #pragma unroll
        for (int j = 0; j < 4; ++j) {
            float v = vv[j];
            if (v > m) { s = s * __expf(m - v) + 1.f; m = v; }
            else       { s += __expf(v - m); }
            if (v > vmax) { vmax = v; vidx = i * 4 + j; }
        }
    }
    __shared__ float sm[256], ss[256], sv[256];
    __shared__ int   si[256];
    sm[t] = m; ss[t] = s; sv[t] = vmax; si[t] = vidx;
    __syncthreads();
    for (int st = 128; st > 0; st >>= 1) {
        if (t < st) {
            float m2 = sm[t + st], s2 = ss[t + st];
            float mn = fmaxf(sm[t], m2);
            ss[t] = ss[t] * __expf(sm[t] - mn) + s2 * __expf(m2 - mn);
            sm[t] = mn;
            float v2 = sv[t + st]; int i2 = si[t + st];
            if (v2 > sv[t] || (v2 == sv[t] && i2 < si[t])) { sv[t] = v2; si[t] = i2; }
        }
        __syncthreads();
    }
    if (t == 0) {
        float vyb = logits[(size_t)b * CLS_N + yb];
        float mv  = mod_val_a[b];
        float M = sm[0], S = ss[0];
        float m2 = fmaxf(M, mv);
        float s2 = S * __expf(M - m2) - __expf(vyb - m2) + __expf(mv - m2);
        float lse = m2 + logf(s2);
        atomicAdd(ce_sum, -(mv - lse));
        if (si[0] == yb) atomicAdd(acc_sum, 1.f);
    }
}

__global__ void finalize_kernel(const float* __restrict__ accums, float* __restrict__ out)
{
    float ce    = accums[0] / (float)B_N;
    float acc   = accums[1] / (float)B_N;
    float inter = accums[2] / (float)((double)B_N * (CLS_N - 1));
    out[0] = ce + 0.01f * inter;
    out[(size_t)1 + (size_t)B_N * CLS_N + 0] = acc;
    out[(size_t)1 + (size_t)B_N * CLS_N + 1] = inter;
}

extern "C" void kernel_launch(void* const* d_in, const int* in_sizes, int n_in,
                              void* d_out, int out_size, void* d_ws, size_t ws_size,
                              hipStream_t stream) {
    const float* emb = (const float*)d_in[0];
    const int*   y   = (const int*)d_in[1];
    const float* W   = (const float*)d_in[2];
    float* out = (float*)d_out;
    float* logits = out + 1;   // [loss, logits(256x20000), acc, inter]

    // fast-path ws layout (bytes)
    const size_t ABF_OFF = 0;                                  // 512*512*2       = 524288
    const size_t WT_OFF  = 524288;                             // 20096*512*2     = 20578304
    const size_t CS_OFF  = WT_OFF + (size_t)CLS_PAD * EMB_N * 2;   // colsumsq 80384
    const size_t SC_OFF  = CS_OFF + (size_t)CLS_PAD * 4;
    const size_t NEEDED  = SC_OFF + 5 * 1024;

    if (ws_size >= NEEDED) {
        unsigned short* Abf = (unsigned short*)((char*)d_ws + ABF_OFF);
        unsigned short* Wt  = (unsigned short*)((char*)d_ws + WT_OFF);
        float* colsumsq   = (float*)((char*)d_ws + CS_OFF);
        float* xlen_a     = (float*)((char*)d_ws + SC_OFF);
        float* inv_xlen_a = xlen_a + 256;
        float* inv_wny_a  = xlen_a + 512;
        float* mod_val_a  = xlen_a + 768;
        float* accums     = xlen_a + 1024;

        hipMemsetAsync(colsumsq, 0, (size_t)CLS_PAD * 4, stream);
        hipMemsetAsync(accums, 0, 3 * sizeof(float), stream);

        prep_kernel<<<B_N, 256, 0, stream>>>(emb, y, W, Abf, nullptr,
                                             xlen_a, inv_xlen_a, inv_wny_a, mod_val_a);
        dim3 cg((CLS_PAD + 255) / 256 + 1, 4);   // 79 x 4 covers c<20224 with guards
        convertW_kernel<<<dim3(79, 4), 256, 0, stream>>>(W, Wt, colsumsq);

        dim3 gg((CLS_N + 127) / 128, 4);          // 157 x 4
        mfma_gemm_kernel<<<gg, 256, 0, stream>>>(Abf, Wt, colsumsq, y,
                                                 xlen_a, inv_xlen_a, inv_wny_a,
                                                 logits, accums + 2);
        row_kernel<<<B_N, 256, 0, stream>>>(logits, y, mod_val_a, accums + 0, accums + 1);
        finalize_kernel<<<1, 1, 0, stream>>>(accums, out);
    } else {
        // fallback: round-1 fp32 path (ws too small for bf16 staging buffers)
        float* ws = (float*)d_ws;
        float* Wg         = ws;
        float* inv_wnorm  = ws + 131072;
        float* xlen_a     = ws + 151104;
        float* inv_xlen_a = ws + 151360;
        float* inv_wny_a  = ws + 151616;
        float* mod_val_a  = ws + 151872;
        float* accums     = ws + 152128;

        hipMemsetAsync(accums, 0, 3 * sizeof(float), stream);
        prep_kernel<<<B_N, 256, 0, stream>>>(emb, y, W, nullptr, Wg,
                                             xlen_a, inv_xlen_a, inv_wny_a, mod_val_a);
        colnorm_kernel<<<(CLS_N + 255) / 256, 256, 0, stream>>>(W, inv_wnorm);
        dim3 ggrid((CLS_N + BN - 1) / BN, B_N / BM);
        gemm_old_kernel<<<ggrid, 256, 0, stream>>>(emb, Wg, W, y, xlen_a, inv_xlen_a,
                                                   inv_wny_a, inv_wnorm, logits, accums + 2);
        row_kernel<<<B_N, 256, 0, stream>>>(logits, y, mod_val_a, accums + 0, accums + 1);
        finalize_kernel<<<1, 1, 0, stream>>>(accums, out);
    }
}

// Round 3
// 84.506 us; speedup vs baseline: 2.4765x; 1.0569x over previous
//
#include <hip/hip_runtime.h>
#include <hip/hip_bf16.h>
#include <math.h>

#define B_N   256
#define EMB_N 512
#define CLS_N 20000
#define CLS_PAD 20096
#define NPART 157
#define PI_F  3.14159265f
#define F_CONST ((float)(1.1 / 1501.1))

typedef __bf16 bf16x8 __attribute__((ext_vector_type(8)));
typedef float  f32x4  __attribute__((ext_vector_type(4)));

__device__ __forceinline__ unsigned short f2bf(float f) {
    unsigned u = __float_as_uint(f);
    unsigned r = (u + 0x7FFFu + ((u >> 16) & 1u)) >> 16;  // RNE
    return (unsigned short)r;
}

// online-softmax + argmax merge
__device__ __forceinline__ void merge4(float& M, float& S, float& VM, int& VI,
                                       float m2, float s2, float vm2, int vi2) {
    float mn = fmaxf(M, m2);
    if (mn == -INFINITY) { S = 0.f; }
    else S = S * __expf(M - mn) + s2 * __expf(m2 - mn);
    M = mn;
    if (vm2 > VM || (vm2 == VM && vi2 < VI)) { VM = vm2; VI = vi2; }
}

// ---------------- prep: per-row scalars + bf16 stacked A ----------------
__global__ __launch_bounds__(256) void prep_kernel(
    const float* __restrict__ emb, const int* __restrict__ y,
    const float* __restrict__ W,
    unsigned short* __restrict__ Abf,
    float* __restrict__ xlen_a, float* __restrict__ inv_xlen_a,
    float* __restrict__ inv_wny_a, float* __restrict__ mod_val_a)
{
    const int b = blockIdx.x;
    const int t = threadIdx.x;
    const int yb = y[b];
    const float* erow = emb + (size_t)b * EMB_N;
    float se = 0.f, sw = 0.f, dt = 0.f;
    for (int e = t; e < EMB_N; e += 256) {
        float ev = erow[e];
        float wv = W[(size_t)e * CLS_N + yb];
        Abf[(size_t)b * EMB_N + e]         = f2bf(ev);
        Abf[(size_t)(B_N + b) * EMB_N + e] = f2bf(wv);
        se += ev * ev; sw += wv * wv; dt += ev * wv;
    }
    __shared__ float r0[256], r1[256], r2[256];
    r0[t] = se; r1[t] = sw; r2[t] = dt;
    __syncthreads();
    for (int s = 128; s > 0; s >>= 1) {
        if (t < s) { r0[t] += r0[t + s]; r1[t] += r1[t + s]; r2[t] += r2[t + s]; }
        __syncthreads();
    }
    if (t == 0) {
        float xlen = sqrtf(r0[0]);
        float wn   = sqrtf(r1[0]);
        float inv_x = 1.f / xlen;
        float inv_w = 1.f / wn;
        float cos_t = r2[0] * inv_w * inv_x;
        cos_t = fminf(1.f, fmaxf(-1.f, cos_t));
        float c2 = cos_t * cos_t;
        float cos_m = 8.f * c2 * c2 - 8.f * c2 + 1.f;
        float theta = acosf(cos_t);
        float k = floorf(4.f * theta / PI_F);
        float sgn = 1.f - 2.f * fmodf(k, 2.f);
        float phi = sgn * cos_m - 2.f * k;
        float cos_s = cos_t * xlen;
        float phi_s = phi * xlen;
        xlen_a[b] = xlen;
        inv_xlen_a[b] = inv_x;
        inv_wny_a[b] = inv_w;
        mod_val_a[b] = cos_s + F_CONST * (phi_s - cos_s);
    }
}

// ---------------- convertW: W[K][N] fp32 -> Wt[N_pad][K] bf16 via LDS transpose ----------------
// grid (157, 4): 128-col x 128-k tile per block. Coalesced read AND write.
__global__ __launch_bounds__(256) void convertW_kernel(
    const float* __restrict__ W, unsigned short* __restrict__ Wt,
    float* __restrict__ colsumsq)
{
    __shared__ unsigned short T[128][136];   // +8 pad: 272B row stride, 16B aligned
    const int t  = threadIdx.x;
    const int c0 = blockIdx.x * 128;
    const int k0 = blockIdx.y * 128;

    const int cl = (t & 31) * 4;          // local col (x4)
    const int kr = t >> 5;                // 0..7
    float ssq[4] = {0.f, 0.f, 0.f, 0.f};

    for (int it = 0; it < 16; ++it) {
        int k = k0 + it * 8 + kr;
        int c = c0 + cl;
        float4 v;
        if (c + 3 < CLS_N) {
            v = *reinterpret_cast<const float4*>(&W[(size_t)k * CLS_N + c]);
        } else {
            v.x = (c + 0 < CLS_N) ? W[(size_t)k * CLS_N + c + 0] : 0.f;
            v.y = (c + 1 < CLS_N) ? W[(size_t)k * CLS_N + c + 1] : 0.f;
            v.z = (c + 2 < CLS_N) ? W[(size_t)k * CLS_N + c + 2] : 0.f;
            v.w = (c + 3 < CLS_N) ? W[(size_t)k * CLS_N + c + 3] : 0.f;
        }
        float vv[4] = {v.x, v.y, v.z, v.w};
        #pragma unroll
        for (int j = 0; j < 4; ++j) {
            ssq[j] += vv[j] * vv[j];
            T[cl + j][it * 8 + kr] = f2bf(vv[j]);
        }
    }
    // per-column global atomic (one thread owns each (c,ktile) pair)
    #pragma unroll
    for (int j = 0; j < 4; ++j) {
        int c = c0 + cl + j;
        if (c < CLS_N) atomicAdd(&colsumsq[c], ssq[j]);
    }
    __syncthreads();

    // coalesced write-out: 16 lanes per Wt row chunk (256B)
    for (int p = 0; p < 8; ++p) {
        int c = p * 16 + (t >> 4);
        uint4 d = *reinterpret_cast<const uint4*>(&T[c][(t & 15) * 8]);
        *reinterpret_cast<uint4*>(&Wt[(size_t)(c0 + c) * EMB_N + k0 + (t & 15) * 8]) = d;
    }
}

// ---------------- MFMA GEMM + fused softmax partials ----------------
// 128x128 tile, BK=64, 4 waves (2x2). global_load_lds (16B) with pre-swizzled
// source (linear LDS dest), double-buffered 2-phase schedule.
__global__ __launch_bounds__(256) void mfma_gemm_kernel(
    const unsigned short* __restrict__ Abf, const unsigned short* __restrict__ Wt,
    const float* __restrict__ colsumsq, const int* __restrict__ y,
    const float* __restrict__ xlen_a, const float* __restrict__ inv_xlen_a,
    const float* __restrict__ inv_wny_a,
    float* __restrict__ logits, float4* __restrict__ partials,
    float* __restrict__ inter_sum)
{
    __shared__ alignas(16) char sA[2][16384];
    __shared__ alignas(16) char sB[2][16384];
    __shared__ float4 sPart[128][2];
    __shared__ float red[256];

    const int t    = threadIdx.x;
    const int lane = t & 63;
    const int wid  = t >> 6;
    const int wr   = wid >> 1;
    const int wc   = wid & 1;
    const int r16  = lane & 15;
    const int kh   = lane >> 4;
    const int m0   = blockIdx.y * 128;
    const int n0   = blockIdx.x * 128;

    const char* Ab = (const char*)Abf;
    const char* Bb = (const char*)Wt;

    f32x4 acc[4][4] = {};

    // staging: wave-issue i covers LDS slot (wid*4+i)*1024 + lane*16
    // logical row = slot*8 + (lane>>3)  (row&7 == lane>>3), source col-byte
    // pre-swizzled so LDS holds the XOR-swizzled layout with a LINEAR dest.
    const int srow = (lane >> 3);
    const int scb  = (((lane & 7) ^ srow) << 4);

    #define STAGE(buf, kt)                                                              \
        _Pragma("unroll")                                                               \
        for (int i = 0; i < 4; ++i) {                                                   \
            int slot = wid * 4 + i;                                                     \
            int row  = slot * 8 + srow;                                                 \
            __builtin_amdgcn_global_load_lds(                                           \
                (const __attribute__((address_space(1))) unsigned int*)                 \
                    (Ab + (size_t)(m0 + row) * 1024 + (kt) * 2 + scb),                  \
                (__attribute__((address_space(3))) unsigned int*)                       \
                    (sA[buf] + slot * 1024),                                            \
                16, 0, 0);                                                              \
            __builtin_amdgcn_global_load_lds(                                           \
                (const __attribute__((address_space(1))) unsigned int*)                 \
                    (Bb + (size_t)(n0 + row) * 1024 + (kt) * 2 + scb),                  \
                (__attribute__((address_space(3))) unsigned int*)                       \
                    (sB[buf] + slot * 1024),                                            \
                16, 0, 0);                                                              \
        }

    STAGE(0, 0)
    __syncthreads();

    int cur = 0;
    for (int t8 = 0; t8 < 8; ++t8) {
        if (t8 < 7) { STAGE(cur ^ 1, (t8 + 1) * 64) }
        #pragma unroll
        for (int kk = 0; kk < 2; ++kk) {
            bf16x8 af[4], bfr[4];
            #pragma unroll
            for (int mi = 0; mi < 4; ++mi) {
                int row = wr * 64 + mi * 16 + r16;
                int off = (row * 128 + kk * 64 + kh * 16) ^ ((row & 7) << 4);
                af[mi] = *reinterpret_cast<const bf16x8*>(sA[cur] + off);
            }
            #pragma unroll
            for (int ni = 0; ni < 4; ++ni) {
                int row = wc * 64 + ni * 16 + r16;
                int off = (row * 128 + kk * 64 + kh * 16) ^ ((row & 7) << 4);
                bfr[ni] = *reinterpret_cast<const bf16x8*>(sB[cur] + off);
            }
            #pragma unroll
            for (int mi = 0; mi < 4; ++mi)
                #pragma unroll
                for (int ni = 0; ni < 4; ++ni)
                    acc[mi][ni] = __builtin_amdgcn_mfma_f32_16x16x32_bf16(
                        af[mi], bfr[ni], acc[mi][ni], 0, 0, 0);
        }
        __syncthreads();
        cur ^= 1;
    }
    #undef STAGE

    int   cc[4]; float iwc[4];
    #pragma unroll
    for (int ni = 0; ni < 4; ++ni) {
        cc[ni] = n0 + wc * 64 + ni * 16 + r16;
        iwc[ni] = (cc[ni] < CLS_N) ? rsqrtf(colsumsq[cc[ni]]) : 0.f;
    }

    if (m0 < B_N) {
        #pragma unroll
        for (int mi = 0; mi < 4; ++mi) {
            int mbase = m0 + wr * 64 + mi * 16 + kh * 4;
            float xl[4], ixl[4];
            #pragma unroll
            for (int r = 0; r < 4; ++r) { xl[r] = xlen_a[mbase + r]; ixl[r] = inv_xlen_a[mbase + r]; }
            float lm[4], ls[4], lvm[4]; int lvi[4];
            #pragma unroll
            for (int r = 0; r < 4; ++r) { lm[r] = -INFINITY; ls[r] = 0.f; lvm[r] = -INFINITY; lvi[r] = 0x7fffffff; }
            #pragma unroll
            for (int ni = 0; ni < 4; ++ni) {
                bool valid = (cc[ni] < CLS_N);
                #pragma unroll
                for (int r = 0; r < 4; ++r) {
                    if (!valid) continue;
                    float cosv = acc[mi][ni][r] * iwc[ni] * ixl[r];
                    cosv = fminf(1.f, fmaxf(-1.f, cosv));
                    float v = cosv * xl[r];
                    logits[(size_t)(mbase + r) * CLS_N + cc[ni]] = v;
                    if (v > lm[r]) { ls[r] = ls[r] * __expf(lm[r] - v) + 1.f; lm[r] = v; }
                    else           { ls[r] += __expf(v - lm[r]); }
                    if (v > lvm[r]) { lvm[r] = v; lvi[r] = cc[ni]; }
                }
            }
            // 16-lane butterfly within r16 group (lanes kh*16 .. kh*16+15)
            #pragma unroll
            for (int r = 0; r < 4; ++r) {
                float M = lm[r], S = ls[r], VM = lvm[r]; int VI = lvi[r];
                #pragma unroll
                for (int d = 1; d < 16; d <<= 1) {
                    float m2  = __shfl_xor(M, d);
                    float s2  = __shfl_xor(S, d);
                    float vm2 = __shfl_xor(VM, d);
                    int   vi2 = __shfl_xor(VI, d);
                    merge4(M, S, VM, VI, m2, s2, vm2, vi2);
                }
                if (r16 == 0) {
                    int R = wr * 64 + mi * 16 + kh * 4 + r;
                    sPart[R][wc] = make_float4(M, S, VM, __int_as_float(VI));
                }
            }
        }
        __syncthreads();
        if (t < 128) {
            float4 p0 = sPart[t][0], p1 = sPart[t][1];
            float M = p0.x, S = p0.y, VM = p0.z; int VI = __float_as_int(p0.w);
            merge4(M, S, VM, VI, p1.x, p1.y, p1.z, __float_as_int(p1.w));
            partials[(size_t)(m0 + t) * NPART + blockIdx.x] =
                make_float4(M, S, VM, __int_as_float(VI));
        }
    } else {
        float part = 0.f;
        #pragma unroll
        for (int mi = 0; mi < 4; ++mi) {
            int bbase = (m0 - B_N) + wr * 64 + mi * 16 + kh * 4;
            float iwy[4]; int yy[4];
            #pragma unroll
            for (int r = 0; r < 4; ++r) { iwy[r] = inv_wny_a[bbase + r]; yy[r] = y[bbase + r]; }
            #pragma unroll
            for (int ni = 0; ni < 4; ++ni) {
                if (cc[ni] >= CLS_N) continue;
                #pragma unroll
                for (int r = 0; r < 4; ++r) {
                    float cww = acc[mi][ni][r] * iwc[ni] * iwy[r];
                    float d2 = fmaxf(2.f - 2.f * cww, 0.f);
                    if (cc[ni] != yy[r]) part += 1.f / d2;
                }
            }
        }
        red[t] = part;
        __syncthreads();
        for (int s = 128; s > 0; s >>= 1) {
            if (t < s) red[t] += red[t + s];
            __syncthreads();
        }
        if (t == 0) atomicAdd(inter_sum, red[0]);
    }
}

// ---------------- reduce: merge 157 partials per row, CE fixup + argmax ----------------
__global__ __launch_bounds__(64) void reduce_kernel(
    const float4* __restrict__ partials, const float* __restrict__ logits,
    const int* __restrict__ y, const float* __restrict__ mod_val_a,
    float* __restrict__ ce_sum, float* __restrict__ acc_sum)
{
    const int b = blockIdx.x;
    const int t = threadIdx.x;
    float M = -INFINITY, S = 0.f, VM = -INFINITY; int VI = 0x7fffffff;
    for (int i = t; i < NPART; i += 64) {
        float4 p = partials[(size_t)b * NPART + i];
        merge4(M, S, VM, VI, p.x, p.y, p.z, __float_as_int(p.w));
    }
    #pragma unroll
    for (int d = 1; d < 64; d <<= 1) {
        float m2  = __shfl_xor(M, d);
        float s2  = __shfl_xor(S, d);
        float vm2 = __shfl_xor(VM, d);
        int   vi2 = __shfl_xor(VI, d);
        merge4(M, S, VM, VI, m2, s2, vm2, vi2);
    }
    if (t == 0) {
        int   yb  = y[b];
        float vyb = logits[(size_t)b * CLS_N + yb];
        float mv  = mod_val_a[b];
        float m2 = fmaxf(M, mv);
        float s2 = S * __expf(M - m2) - __expf(vyb - m2) + __expf(mv - m2);
        float lse = m2 + logf(s2);
        atomicAdd(ce_sum, -(mv - lse));
        if (VI == yb) atomicAdd(acc_sum, 1.f);
    }
}

__global__ void finalize_kernel(const float* __restrict__ accums, float* __restrict__ out)
{
    float ce    = accums[0] / (float)B_N;
    float acc   = accums[1] / (float)B_N;
    float inter = accums[2] / (float)((double)B_N * (CLS_N - 1));
    out[0] = ce + 0.01f * inter;
    out[(size_t)1 + (size_t)B_N * CLS_N + 0] = acc;
    out[(size_t)1 + (size_t)B_N * CLS_N + 1] = inter;
}

extern "C" void kernel_launch(void* const* d_in, const int* in_sizes, int n_in,
                              void* d_out, int out_size, void* d_ws, size_t ws_size,
                              hipStream_t stream) {
    const float* emb = (const float*)d_in[0];
    const int*   y   = (const int*)d_in[1];
    const float* W   = (const float*)d_in[2];
    float* out = (float*)d_out;
    float* logits = out + 1;   // [loss, logits(256x20000), acc, inter]

    // ws layout (bytes)
    const size_t ABF_OFF  = 0;                                        // 524288
    const size_t WT_OFF   = 524288;                                   // 20096*512*2
    const size_t CS_OFF   = WT_OFF + (size_t)CLS_PAD * EMB_N * 2;     // 80384
    const size_t PART_OFF = CS_OFF + (size_t)CLS_PAD * 4;             // 256*157*16
    const size_t SC_OFF   = PART_OFF + (size_t)B_N * NPART * 16;

    unsigned short* Abf = (unsigned short*)((char*)d_ws + ABF_OFF);
    unsigned short* Wt  = (unsigned short*)((char*)d_ws + WT_OFF);
    float*  colsumsq   = (float*)((char*)d_ws + CS_OFF);
    float4* partials   = (float4*)((char*)d_ws + PART_OFF);
    float*  xlen_a     = (float*)((char*)d_ws + SC_OFF);
    float*  inv_xlen_a = xlen_a + 256;
    float*  inv_wny_a  = xlen_a + 512;
    float*  mod_val_a  = xlen_a + 768;
    float*  accums     = xlen_a + 1024;

    hipMemsetAsync(colsumsq, 0, (size_t)CLS_PAD * 4, stream);
    hipMemsetAsync(accums, 0, 3 * sizeof(float), stream);

    prep_kernel<<<B_N, 256, 0, stream>>>(emb, y, W, Abf,
                                         xlen_a, inv_xlen_a, inv_wny_a, mod_val_a);
    convertW_kernel<<<dim3(NPART, 4), 256, 0, stream>>>(W, Wt, colsumsq);

    dim3 gg(NPART, 4);
    mfma_gemm_kernel<<<gg, 256, 0, stream>>>(Abf, Wt, colsumsq, y,
                                             xlen_a, inv_xlen_a, inv_wny_a,
                                             logits, partials, accums + 2);
    reduce_kernel<<<B_N, 64, 0, stream>>>(partials, logits, y, mod_val_a,
                                          accums + 0, accums + 1);
    finalize_kernel<<<1, 1, 0, stream>>>(accums, out);
}

// Round 4
// 81.722 us; speedup vs baseline: 2.5608x; 1.0341x over previous
//
#include <hip/hip_runtime.h>
#include <hip/hip_bf16.h>
#include <math.h>

#define B_N   256
#define EMB_N 512
#define CLS_N 20000
#define CLS_PAD 20096
#define NMB   313          // class tiles of 64 (313*64 = 20032 >= 20000)
#define PI_F  3.14159265f
#define F_CONST ((float)(1.1 / 1501.1))

typedef __bf16 bf16x8 __attribute__((ext_vector_type(8)));
typedef float  f32x4  __attribute__((ext_vector_type(4)));

__device__ __forceinline__ unsigned short f2bf(float f) {
    unsigned u = __float_as_uint(f);
    unsigned r = (u + 0x7FFFu + ((u >> 16) & 1u)) >> 16;  // RNE
    return (unsigned short)r;
}

__device__ __forceinline__ void merge4(float& M, float& S, float& VM, int& VI,
                                       float m2, float s2, float vm2, int vi2) {
    float mn = fmaxf(M, m2);
    if (mn == -INFINITY) { S = 0.f; }
    else S = S * __expf(M - mn) + s2 * __expf(m2 - mn);
    M = mn;
    if (vm2 > VM || (vm2 == VM && vi2 < VI)) { VM = vm2; VI = vi2; }
}

// ---------------- prep: per-row scalars + bf16 stacked A (batch operand) ----------------
__global__ __launch_bounds__(256) void prep_kernel(
    const float* __restrict__ emb, const int* __restrict__ y,
    const float* __restrict__ W,
    unsigned short* __restrict__ Abf,
    float* __restrict__ xlen_a, float* __restrict__ inv_xlen_a,
    float* __restrict__ inv_wny_a, float* __restrict__ mod_val_a)
{
    const int b = blockIdx.x;
    const int t = threadIdx.x;
    const int yb = y[b];
    const float* erow = emb + (size_t)b * EMB_N;
    float se = 0.f, sw = 0.f, dt = 0.f;
    for (int e = t; e < EMB_N; e += 256) {
        float ev = erow[e];
        float wv = W[(size_t)e * CLS_N + yb];
        Abf[(size_t)b * EMB_N + e]         = f2bf(ev);
        Abf[(size_t)(B_N + b) * EMB_N + e] = f2bf(wv);
        se += ev * ev; sw += wv * wv; dt += ev * wv;
    }
    __shared__ float r0[256], r1[256], r2[256];
    r0[t] = se; r1[t] = sw; r2[t] = dt;
    __syncthreads();
    for (int s = 128; s > 0; s >>= 1) {
        if (t < s) { r0[t] += r0[t + s]; r1[t] += r1[t + s]; r2[t] += r2[t + s]; }
        __syncthreads();
    }
    if (t == 0) {
        float xlen = sqrtf(r0[0]);
        float wn   = sqrtf(r1[0]);
        float inv_x = 1.f / xlen;
        float inv_w = 1.f / wn;
        float cos_t = r2[0] * inv_w * inv_x;
        cos_t = fminf(1.f, fmaxf(-1.f, cos_t));
        float c2 = cos_t * cos_t;
        float cos_m = 8.f * c2 * c2 - 8.f * c2 + 1.f;
        float theta = acosf(cos_t);
        float k = floorf(4.f * theta / PI_F);
        float sgn = 1.f - 2.f * fmodf(k, 2.f);
        float phi = sgn * cos_m - 2.f * k;
        float cos_s = cos_t * xlen;
        float phi_s = phi * xlen;
        xlen_a[b] = xlen;
        inv_xlen_a[b] = inv_x;
        inv_wny_a[b] = inv_w;
        mod_val_a[b] = cos_s + F_CONST * (phi_s - cos_s);
    }
}

// ---------------- convertW: W[K][N] fp32 -> Wt[N_pad][K] bf16 via LDS transpose ----------------
__global__ __launch_bounds__(256) void convertW_kernel(
    const float* __restrict__ W, unsigned short* __restrict__ Wt,
    float* __restrict__ colsumsq)
{
    __shared__ unsigned short T[128][136];
    const int t  = threadIdx.x;
    const int c0 = blockIdx.x * 128;
    const int k0 = blockIdx.y * 128;

    const int cl = (t & 31) * 4;
    const int kr = t >> 5;
    float ssq[4] = {0.f, 0.f, 0.f, 0.f};

    for (int it = 0; it < 16; ++it) {
        int k = k0 + it * 8 + kr;
        int c = c0 + cl;
        float4 v;
        if (c + 3 < CLS_N) {
            v = *reinterpret_cast<const float4*>(&W[(size_t)k * CLS_N + c]);
        } else {
            v.x = (c + 0 < CLS_N) ? W[(size_t)k * CLS_N + c + 0] : 0.f;
            v.y = (c + 1 < CLS_N) ? W[(size_t)k * CLS_N + c + 1] : 0.f;
            v.z = (c + 2 < CLS_N) ? W[(size_t)k * CLS_N + c + 2] : 0.f;
            v.w = (c + 3 < CLS_N) ? W[(size_t)k * CLS_N + c + 3] : 0.f;
        }
        float vv[4] = {v.x, v.y, v.z, v.w};
        #pragma unroll
        for (int j = 0; j < 4; ++j) {
            ssq[j] += vv[j] * vv[j];
            T[cl + j][it * 8 + kr] = f2bf(vv[j]);
        }
    }
    #pragma unroll
    for (int j = 0; j < 4; ++j) {
        int c = c0 + cl + j;
        if (c < CLS_N) atomicAdd(&colsumsq[c], ssq[j]);
    }
    __syncthreads();

    for (int p = 0; p < 8; ++p) {
        int c = p * 16 + (t >> 4);
        uint4 d = *reinterpret_cast<const uint4*>(&T[c][(t & 15) * 8]);
        *reinterpret_cast<uint4*>(&Wt[(size_t)(c0 + c) * EMB_N + k0 + (t & 15) * 8]) = d;
    }
}

// ---------------- MFMA GEMM (transposed): classes = M, stacked batch = N ----------------
// Tile 64(classes) x 128(batch), BK=64, single LDS buffer, 4 waves (2Mx2N).
// XCD-chunked swizzle: bid%8 = XCD owns contiguous class range, n fastest.
__global__ __launch_bounds__(256, 4) void mfma_gemm_kernel(
    const unsigned short* __restrict__ Wt, const unsigned short* __restrict__ Abf,
    const float* __restrict__ colsumsq, const int* __restrict__ y,
    const float* __restrict__ xlen_a, const float* __restrict__ inv_xlen_a,
    const float* __restrict__ inv_wny_a,
    float* __restrict__ logits, float4* __restrict__ partials,
    float* __restrict__ inter_sum)
{
    __shared__ alignas(16) char sA[8192];    // 64 class rows x 128B (swizzled)
    __shared__ alignas(16) char sB[16384];   // 128 batch rows x 128B
    __shared__ float4 sPart[128][2];
    __shared__ float red[256];

    const int bid = blockIdx.x;
    const int c8  = bid & 7;
    const int j   = bid >> 3;          // 0..159
    const int m_blk = c8 * 40 + (j >> 2);
    const int nb    = j & 3;           // 0,1: logits halves; 2,3: MHE halves
    if (m_blk >= NMB) return;

    const int t    = threadIdx.x;
    const int lane = t & 63;
    const int wid  = t >> 6;
    const int wr   = wid >> 1;         // class half (32 rows)
    const int wc   = wid & 1;          // batch half (64 cols)
    const int r16  = lane & 15;
    const int kh   = lane >> 4;
    const int m0   = m_blk * 64;       // class base
    const int gn0  = nb * 128;         // stacked-batch base

    const char* Ab = (const char*)Wt;
    const char* Bb = (const char*)Abf;

    f32x4 acc[2][4] = {};

    const int srow = (lane >> 3);
    const int scb  = (((lane & 7) ^ srow) << 4);

    for (int kt = 0; kt < EMB_N; kt += 64) {
        #pragma unroll
        for (int i = 0; i < 2; ++i) {
            int slot = wid * 2 + i;
            int row  = slot * 8 + srow;
            __builtin_amdgcn_global_load_lds(
                (const __attribute__((address_space(1))) unsigned int*)
                    (Ab + (size_t)(m0 + row) * 1024 + (size_t)kt * 2 + scb),
                (__attribute__((address_space(3))) unsigned int*)(sA + slot * 1024),
                16, 0, 0);
        }
        #pragma unroll
        for (int i = 0; i < 4; ++i) {
            int slot = wid * 4 + i;
            int row  = slot * 8 + srow;
            __builtin_amdgcn_global_load_lds(
                (const __attribute__((address_space(1))) unsigned int*)
                    (Bb + (size_t)(gn0 + row) * 1024 + (size_t)kt * 2 + scb),
                (__attribute__((address_space(3))) unsigned int*)(sB + slot * 1024),
                16, 0, 0);
        }
        __syncthreads();
        #pragma unroll
        for (int kk = 0; kk < 2; ++kk) {
            bf16x8 af[2], bfr[4];
            #pragma unroll
            for (int mi = 0; mi < 2; ++mi) {
                int row = wr * 32 + mi * 16 + r16;
                int off = (row * 128 + kk * 64 + kh * 16) ^ ((row & 7) << 4);
                af[mi] = *reinterpret_cast<const bf16x8*>(sA + off);
            }
            #pragma unroll
            for (int ni = 0; ni < 4; ++ni) {
                int row = wc * 64 + ni * 16 + r16;
                int off = (row * 128 + kk * 64 + kh * 16) ^ ((row & 7) << 4);
                bfr[ni] = *reinterpret_cast<const bf16x8*>(sB + off);
            }
            #pragma unroll
            for (int mi = 0; mi < 2; ++mi)
                #pragma unroll
                for (int ni = 0; ni < 4; ++ni)
                    acc[mi][ni] = __builtin_amdgcn_mfma_f32_16x16x32_bf16(
                        af[mi], bfr[ni], acc[mi][ni], 0, 0, 0);
        }
        __syncthreads();
    }

    // per-thread class bases + inverse column norms (4 consecutive classes per reg-quad)
    int   cbase[2];
    float iwc[2][4];
    #pragma unroll
    for (int mi = 0; mi < 2; ++mi) {
        int cb = m0 + wr * 32 + mi * 16 + kh * 4;
        cbase[mi] = cb;
        f32x4 cs = *reinterpret_cast<const f32x4*>(&colsumsq[cb]);
        #pragma unroll
        for (int r = 0; r < 4; ++r) iwc[mi][r] = rsqrtf(cs[r]);
    }

    if (nb < 2) {
        // ---- logits + fused per-thread softmax/argmax over classes ----
        #pragma unroll
        for (int ni = 0; ni < 4; ++ni) {
            int bl = wc * 64 + ni * 16 + r16;   // 0..127 within block
            int b  = gn0 + bl;                  // global batch row
            float xl  = xlen_a[b];
            float ixl = inv_xlen_a[b];
            float M = -INFINITY, S = 0.f, VM = -INFINITY; int VI = 0x7fffffff;
            #pragma unroll
            for (int mi = 0; mi < 2; ++mi) {
                int cb = cbase[mi];
                f32x4 vout;
                #pragma unroll
                for (int r = 0; r < 4; ++r) {
                    float cosv = acc[mi][ni][r] * iwc[mi][r] * ixl;
                    cosv = fminf(1.f, fmaxf(-1.f, cosv));
                    float v = cosv * xl;
                    vout[r] = v;
                    if (cb + r < CLS_N) {
                        if (v > M) { S = S * __expf(M - v) + 1.f; M = v; }
                        else       { S += __expf(v - M); }
                        if (v > VM) { VM = v; VI = cb + r; }
                    }
                }
                if (cb + 3 < CLS_N) {
                    __builtin_nontemporal_store(vout,
                        reinterpret_cast<f32x4*>(&logits[(size_t)b * CLS_N + cb]));
                } else {
                    #pragma unroll
                    for (int r = 0; r < 4; ++r)
                        if (cb + r < CLS_N) logits[(size_t)b * CLS_N + cb + r] = vout[r];
                }
            }
            // merge across kh groups (lanes l, l^16, l^32, l^48)
            #pragma unroll
            for (int d = 16; d < 64; d <<= 1) {
                float m2  = __shfl_xor(M, d);
                float s2  = __shfl_xor(S, d);
                float vm2 = __shfl_xor(VM, d);
                int   vi2 = __shfl_xor(VI, d);
                merge4(M, S, VM, VI, m2, s2, vm2, vi2);
            }
            if (kh == 0) sPart[bl][wr] = make_float4(M, S, VM, __int_as_float(VI));
        }
        __syncthreads();
        if (t < 128) {
            float4 p0 = sPart[t][0], p1 = sPart[t][1];
            float M = p0.x, S = p0.y, VM = p0.z; int VI = __float_as_int(p0.w);
            merge4(M, S, VM, VI, p1.x, p1.y, p1.z, __float_as_int(p1.w));
            partials[(size_t)(gn0 + t) * NMB + m_blk] =
                make_float4(M, S, VM, __int_as_float(VI));
        }
    } else {
        // ---- MHE inter-class term ----
        int b0 = (nb - 2) * 128;
        float part = 0.f;
        #pragma unroll
        for (int ni = 0; ni < 4; ++ni) {
            int b = b0 + wc * 64 + ni * 16 + r16;
            float iwy = inv_wny_a[b];
            int   yb  = y[b];
            #pragma unroll
            for (int mi = 0; mi < 2; ++mi) {
                int cb = cbase[mi];
                #pragma unroll
                for (int r = 0; r < 4; ++r) {
                    int c = cb + r;
                    if (c < CLS_N && c != yb) {
                        float cww = acc[mi][ni][r] * iwc[mi][r] * iwy;
                        float d2 = fmaxf(2.f - 2.f * cww, 0.f);
                        part += 1.f / d2;
                    }
                }
            }
        }
        red[t] = part;
        __syncthreads();
        for (int s = 128; s > 0; s >>= 1) {
            if (t < s) red[t] += red[t + s];
            __syncthreads();
        }
        if (t == 0) atomicAdd(inter_sum, red[0]);
    }
}

// ---------------- reduce: merge NMB partials per batch row, CE fixup + argmax ----------------
__global__ __launch_bounds__(64) void reduce_kernel(
    const float4* __restrict__ partials, const float* __restrict__ logits,
    const int* __restrict__ y, const float* __restrict__ mod_val_a,
    float* __restrict__ ce_sum, float* __restrict__ acc_sum)
{
    const int b = blockIdx.x;
    const int t = threadIdx.x;
    float M = -INFINITY, S = 0.f, VM = -INFINITY; int VI = 0x7fffffff;
    for (int i = t; i < NMB; i += 64) {
        float4 p = partials[(size_t)b * NMB + i];
        merge4(M, S, VM, VI, p.x, p.y, p.z, __float_as_int(p.w));
    }
    #pragma unroll
    for (int d = 1; d < 64; d <<= 1) {
        float m2  = __shfl_xor(M, d);
        float s2  = __shfl_xor(S, d);
        float vm2 = __shfl_xor(VM, d);
        int   vi2 = __shfl_xor(VI, d);
        merge4(M, S, VM, VI, m2, s2, vm2, vi2);
    }
    if (t == 0) {
        int   yb  = y[b];
        float vyb = logits[(size_t)b * CLS_N + yb];
        float mv  = mod_val_a[b];
        float m2 = fmaxf(M, mv);
        float s2 = S * __expf(M - m2) - __expf(vyb - m2) + __expf(mv - m2);
        float lse = m2 + logf(s2);
        atomicAdd(ce_sum, -(mv - lse));
        if (VI == yb) atomicAdd(acc_sum, 1.f);
    }
}

__global__ void finalize_kernel(const float* __restrict__ accums, float* __restrict__ out)
{
    float ce    = accums[0] / (float)B_N;
    float acc   = accums[1] / (float)B_N;
    float inter = accums[2] / (float)((double)B_N * (CLS_N - 1));
    out[0] = ce + 0.01f * inter;
    out[(size_t)1 + (size_t)B_N * CLS_N + 0] = acc;
    out[(size_t)1 + (size_t)B_N * CLS_N + 1] = inter;
}

extern "C" void kernel_launch(void* const* d_in, const int* in_sizes, int n_in,
                              void* d_out, int out_size, void* d_ws, size_t ws_size,
                              hipStream_t stream) {
    const float* emb = (const float*)d_in[0];
    const int*   y   = (const int*)d_in[1];
    const float* W   = (const float*)d_in[2];
    float* out = (float*)d_out;
    float* logits = out + 1;   // [loss, logits(256x20000), acc, inter]

    // ws layout (bytes)
    const size_t ABF_OFF  = 0;                                     // 524288
    const size_t WT_OFF   = 524288;                                // 20096*512*2
    const size_t CS_OFF   = WT_OFF + (size_t)CLS_PAD * EMB_N * 2;  // 80384
    const size_t PART_OFF = CS_OFF + (size_t)CLS_PAD * 4;          // 256*313*16
    const size_t SC_OFF   = PART_OFF + (size_t)B_N * NMB * 16;

    unsigned short* Abf = (unsigned short*)((char*)d_ws + ABF_OFF);
    unsigned short* Wt  = (unsigned short*)((char*)d_ws + WT_OFF);
    float*  colsumsq   = (float*)((char*)d_ws + CS_OFF);
    float4* partials   = (float4*)((char*)d_ws + PART_OFF);
    float*  xlen_a     = (float*)((char*)d_ws + SC_OFF);
    float*  inv_xlen_a = xlen_a + 256;
    float*  inv_wny_a  = xlen_a + 512;
    float*  mod_val_a  = xlen_a + 768;
    float*  accums     = xlen_a + 1024;

    hipMemsetAsync(colsumsq, 0, (size_t)CLS_PAD * 4, stream);
    hipMemsetAsync(accums, 0, 3 * sizeof(float), stream);

    prep_kernel<<<B_N, 256, 0, stream>>>(emb, y, W, Abf,
                                         xlen_a, inv_xlen_a, inv_wny_a, mod_val_a);
    convertW_kernel<<<dim3(157, 4), 256, 0, stream>>>(W, Wt, colsumsq);

    mfma_gemm_kernel<<<1280, 256, 0, stream>>>(Wt, Abf, colsumsq, y,
                                               xlen_a, inv_xlen_a, inv_wny_a,
                                               logits, partials, accums + 2);
    reduce_kernel<<<B_N, 64, 0, stream>>>(partials, logits, y, mod_val_a,
                                          accums + 0, accums + 1);
    finalize_kernel<<<1, 1, 0, stream>>>(accums, out);
}

// Round 6
// 78.592 us; speedup vs baseline: 2.6628x; 1.0398x over previous
//
#include <hip/hip_runtime.h>
#include <hip/hip_bf16.h>
#include <math.h>

#define B_N   256
#define EMB_N 512
#define CLS_N 20000
#define NMB   313          // class tiles of 64 (313*64 = 20032 >= 20000)
#define PI_F  3.14159265f
#define F_CONST ((float)(1.1 / 1501.1))

typedef __bf16 bf16x8 __attribute__((ext_vector_type(8)));
typedef float  f32x4  __attribute__((ext_vector_type(4)));
typedef unsigned short u16x4 __attribute__((ext_vector_type(4)));

__device__ __forceinline__ unsigned short f2bf(float f) {
    unsigned u = __float_as_uint(f);
    unsigned r = (u + 0x7FFFu + ((u >> 16) & 1u)) >> 16;  // RNE
    return (unsigned short)r;
}

__device__ __forceinline__ void merge4(float& M, float& S, float& VM, int& VI,
                                       float m2, float s2, float vm2, int vi2) {
    float mn = fmaxf(M, m2);
    if (mn == -INFINITY) { S = 0.f; }
    else S = S * __expf(M - mn) + s2 * __expf(m2 - mn);
    M = mn;
    if (vm2 > VM || (vm2 == VM && vi2 < VI)) { VM = vm2; VI = vi2; }
}

// ---------------- prep: per-row scalars + bf16 stacked A (batch operand) ----------------
__global__ __launch_bounds__(256) void prep_kernel(
    const float* __restrict__ emb, const int* __restrict__ y,
    const float* __restrict__ W,
    unsigned short* __restrict__ Abf,
    float* __restrict__ xlen_a, float* __restrict__ inv_xlen_a,
    float* __restrict__ inv_wny_a, float* __restrict__ mod_val_a)
{
    const int b = blockIdx.x;
    const int t = threadIdx.x;
    const int yb = y[b];
    const float* erow = emb + (size_t)b * EMB_N;
    float se = 0.f, sw = 0.f, dt = 0.f;
    for (int e = t; e < EMB_N; e += 256) {
        float ev = erow[e];
        float wv = W[(size_t)e * CLS_N + yb];
        Abf[(size_t)b * EMB_N + e]         = f2bf(ev);
        Abf[(size_t)(B_N + b) * EMB_N + e] = f2bf(wv);
        se += ev * ev; sw += wv * wv; dt += ev * wv;
    }
    __shared__ float r0[256], r1[256], r2[256];
    r0[t] = se; r1[t] = sw; r2[t] = dt;
    __syncthreads();
    for (int s = 128; s > 0; s >>= 1) {
        if (t < s) { r0[t] += r0[t + s]; r1[t] += r1[t + s]; r2[t] += r2[t + s]; }
        __syncthreads();
    }
    if (t == 0) {
        float xlen = sqrtf(r0[0]);
        float wn   = sqrtf(r1[0]);
        float inv_x = 1.f / xlen;
        float inv_w = 1.f / wn;
        float cos_t = r2[0] * inv_w * inv_x;
        cos_t = fminf(1.f, fmaxf(-1.f, cos_t));
        float c2 = cos_t * cos_t;
        float cos_m = 8.f * c2 * c2 - 8.f * c2 + 1.f;
        float theta = acosf(cos_t);
        float k = floorf(4.f * theta / PI_F);
        float sgn = 1.f - 2.f * fmodf(k, 2.f);
        float phi = sgn * cos_m - 2.f * k;
        float cos_s = cos_t * xlen;
        float phi_s = phi * xlen;
        xlen_a[b] = xlen;
        inv_xlen_a[b] = inv_x;
        inv_wny_a[b] = inv_w;
        mod_val_a[b] = cos_s + F_CONST * (phi_s - cos_s);
    }
}

// ---------------- fused MFMA GEMM: reads W fp32 directly, transposes in-register ----------------
// Counted-vmcnt 2-phase pipeline. ALL barriers are compile-time memory fences
// (asm s_barrier + memory clobber + sched_barrier) so no LDS op crosses a phase.
__global__ __launch_bounds__(256, 3) void mfma_gemm_kernel(
    const float* __restrict__ W, const unsigned short* __restrict__ Abf,
    const int* __restrict__ y,
    const float* __restrict__ xlen_a, const float* __restrict__ inv_xlen_a,
    const float* __restrict__ inv_wny_a,
    float* __restrict__ logits, float4* __restrict__ partials,
    float* __restrict__ inter_sum)
{
    __shared__ alignas(16) char sA[8192];        // 64 class rows x 128B (swizzled bf16)
    __shared__ alignas(16) char sB[2][16384];    // 128 batch rows x 128B, double-buffered
    __shared__ float  sSq[16][64];
    __shared__ float  sIwc[64];
    __shared__ float4 sPart[128][2];
    __shared__ float  red[256];

    const int bid = blockIdx.x;
    const int c8  = bid & 7;
    const int j   = bid >> 3;
    const int m_blk = c8 * 40 + (j >> 2);
    const int nb    = j & 3;            // 0,1: logits halves; 2,3: MHE halves
    if (m_blk >= NMB) return;

    const int t    = threadIdx.x;
    const int lane = t & 63;
    const int wid  = t >> 6;
    const int wr   = wid >> 1;          // class half (32 rows)
    const int wc   = wid & 1;           // batch half (64 cols)
    const int r16  = lane & 15;
    const int kh   = lane >> 4;
    const int m0   = m_blk * 64;        // class base
    const int gn0  = nb * 128;          // stacked-batch base

    const char* Bb = (const char*)Abf;

    f32x4 acc[2][4] = {};
    float ssq[4] = {0.f, 0.f, 0.f, 0.f};

    // A staging map: thread covers classes sc4..sc4+3, k's sk4..sk4+3 per step
    const int sc4 = (t & 15) * 4;
    const int sk4 = (t >> 4) * 4;
    const int gc4 = min(m0 + sc4, CLS_N - 4);   // clamped (tail block rows masked later)

    // B staging map (pre-swizzled source, linear LDS dest)
    const int srow = (lane >> 3);
    const int scb  = (((lane & 7) ^ srow) << 4);

    // compile-time-fenced barrier: no memory op may cross, vmcnt NOT drained
    #define BARRIER_FENCED()                                   \
        { __builtin_amdgcn_sched_barrier(0);                   \
          asm volatile("s_barrier" ::: "memory");              \
          __builtin_amdgcn_sched_barrier(0); }

    #define ISSUE_B(kt, bufidx)                                                   \
        { _Pragma("unroll")                                                       \
          for (int i = 0; i < 4; ++i) {                                           \
              int slot = wid * 4 + i;                                             \
              int row  = slot * 8 + srow;                                         \
              __builtin_amdgcn_global_load_lds(                                   \
                  (const __attribute__((address_space(1))) unsigned int*)         \
                      (Bb + (size_t)(gn0 + row) * 1024 + (size_t)(kt) * 2 + scb), \
                  (__attribute__((address_space(3))) unsigned int*)               \
                      (sB[bufidx] + slot * 1024),                                 \
                  16, 0, 0);                                                      \
          } }

    #define ISSUE_A(kt, dst)                                                      \
        { _Pragma("unroll")                                                       \
          for (int p = 0; p < 4; ++p)                                             \
              dst[p] = *reinterpret_cast<const f32x4*>(                           \
                  &W[(size_t)((kt) + sk4 + p) * CLS_N + gc4]);                    \
        }

    #define WRITE_A(src)                                                          \
        { _Pragma("unroll")                                                       \
          for (int jj = 0; jj < 4; ++jj) {                                        \
              u16x4 u;                                                            \
              u[0] = f2bf(src[0][jj]); u[1] = f2bf(src[1][jj]);                   \
              u[2] = f2bf(src[2][jj]); u[3] = f2bf(src[3][jj]);                   \
              ssq[jj] += src[0][jj] * src[0][jj] + src[1][jj] * src[1][jj]        \
                       + src[2][jj] * src[2][jj] + src[3][jj] * src[3][jj];       \
              int c = sc4 + jj;                                                   \
              int byo = (c * 128 + sk4 * 2) ^ ((c & 7) << 4);                     \
              *reinterpret_cast<u16x4*>(sA + byo) = u;                            \
          } }

    #define COMPUTE(bufptr)                                                       \
        { _Pragma("unroll")                                                       \
          for (int kk = 0; kk < 2; ++kk) {                                        \
              bf16x8 af[2], bfr[4];                                               \
              _Pragma("unroll")                                                   \
              for (int mi = 0; mi < 2; ++mi) {                                    \
                  int row = wr * 32 + mi * 16 + r16;                              \
                  int off = (row * 128 + kk * 64 + kh * 16) ^ ((row & 7) << 4);   \
                  af[mi] = *reinterpret_cast<const bf16x8*>(sA + off);            \
              }                                                                   \
              _Pragma("unroll")                                                   \
              for (int ni = 0; ni < 4; ++ni) {                                    \
                  int row = wc * 64 + ni * 16 + r16;                              \
                  int off = (row * 128 + kk * 64 + kh * 16) ^ ((row & 7) << 4);   \
                  bfr[ni] = *reinterpret_cast<const bf16x8*>((bufptr) + off);     \
              }                                                                   \
              _Pragma("unroll")                                                   \
              for (int mi = 0; mi < 2; ++mi)                                      \
                  _Pragma("unroll")                                               \
                  for (int ni = 0; ni < 4; ++ni)                                  \
                      acc[mi][ni] = __builtin_amdgcn_mfma_f32_16x16x32_bf16(      \
                          af[mi], bfr[ni], acc[mi][ni], 0, 0, 0);                 \
          } }

    f32x4 acur[4], anx[4];
    ISSUE_B(0, 0)
    ISSUE_A(0, acur)

    #pragma unroll
    for (int t8 = 0; t8 < 8; ++t8) {
        if (t8 < 7) {
            ISSUE_B((t8 + 1) * 64, (t8 & 1) ^ 1)
            ISSUE_A((t8 + 1) * 64, anx)
        }
        WRITE_A(acur)
        // counted wait: next-step loads (4 DMA + 4 reg) stay in flight across the barrier
        if (t8 < 7) asm volatile("s_waitcnt vmcnt(8) lgkmcnt(0)" ::: "memory");
        else        asm volatile("s_waitcnt vmcnt(0) lgkmcnt(0)" ::: "memory");
        BARRIER_FENCED()
        COMPUTE(sB[t8 & 1])
        BARRIER_FENCED()
        #pragma unroll
        for (int p = 0; p < 4; ++p) acur[p] = anx[p];
    }
    #undef ISSUE_B
    #undef ISSUE_A
    #undef WRITE_A
    #undef COMPUTE
    #undef BARRIER_FENCED

    // ---- per-class inverse norms from in-kernel sumsq ----
    #pragma unroll
    for (int jj = 0; jj < 4; ++jj) sSq[t >> 4][sc4 + jj] = ssq[jj];
    __syncthreads();
    if (t < 64) {
        float s = 0.f;
        #pragma unroll
        for (int g = 0; g < 16; ++g) s += sSq[g][t];
        sIwc[t] = rsqrtf(s);
    }
    __syncthreads();

    int   lb[2];
    float iwc[2][4];
    #pragma unroll
    for (int mi = 0; mi < 2; ++mi) {
        lb[mi] = wr * 32 + mi * 16 + kh * 4;
        #pragma unroll
        for (int r = 0; r < 4; ++r) iwc[mi][r] = sIwc[lb[mi] + r];
    }

    if (nb < 2) {
        // ---- logits + fused per-thread softmax/argmax over classes ----
        #pragma unroll
        for (int ni = 0; ni < 4; ++ni) {
            int bl = wc * 64 + ni * 16 + r16;
            int b  = gn0 + bl;
            float xl  = xlen_a[b];
            float ixl = inv_xlen_a[b];
            float M = -INFINITY, S = 0.f, VM = -INFINITY; int VI = 0x7fffffff;
            #pragma unroll
            for (int mi = 0; mi < 2; ++mi) {
                int cb = m0 + lb[mi];
                f32x4 vout;
                #pragma unroll
                for (int r = 0; r < 4; ++r) {
                    float cosv = acc[mi][ni][r] * iwc[mi][r] * ixl;
                    cosv = fminf(1.f, fmaxf(-1.f, cosv));
                    float v = cosv * xl;
                    vout[r] = v;
                    if (cb + r < CLS_N) {
                        if (v > M) { S = S * __expf(M - v) + 1.f; M = v; }
                        else       { S += __expf(v - M); }
                        if (v > VM) { VM = v; VI = cb + r; }
                    }
                }
                if (cb + 3 < CLS_N) {
                    __builtin_nontemporal_store(vout,
                        reinterpret_cast<f32x4*>(&logits[(size_t)b * CLS_N + cb]));
                } else {
                    #pragma unroll
                    for (int r = 0; r < 4; ++r)
                        if (cb + r < CLS_N) logits[(size_t)b * CLS_N + cb + r] = vout[r];
                }
            }
            #pragma unroll
            for (int d = 16; d < 64; d <<= 1) {
                float m2  = __shfl_xor(M, d);
                float s2  = __shfl_xor(S, d);
                float vm2 = __shfl_xor(VM, d);
                int   vi2 = __shfl_xor(VI, d);
                merge4(M, S, VM, VI, m2, s2, vm2, vi2);
            }
            if (kh == 0) sPart[bl][wr] = make_float4(M, S, VM, __int_as_float(VI));
        }
        __syncthreads();
        if (t < 128) {
            float4 p0 = sPart[t][0], p1 = sPart[t][1];
            float M = p0.x, S = p0.y, VM = p0.z; int VI = __float_as_int(p0.w);
            merge4(M, S, VM, VI, p1.x, p1.y, p1.z, __float_as_int(p1.w));
            partials[(size_t)(gn0 + t) * NMB + m_blk] =
                make_float4(M, S, VM, __int_as_float(VI));
        }
    } else {
        // ---- MHE inter-class term ----
        int b0 = (nb - 2) * 128;
        float part = 0.f;
        #pragma unroll
        for (int ni = 0; ni < 4; ++ni) {
            int b = b0 + wc * 64 + ni * 16 + r16;
            float iwy = inv_wny_a[b];
            int   yb  = y[b];
            #pragma unroll
            for (int mi = 0; mi < 2; ++mi) {
                int cb = m0 + lb[mi];
                #pragma unroll
                for (int r = 0; r < 4; ++r) {
                    int c = cb + r;
                    if (c < CLS_N && c != yb) {
                        float cww = acc[mi][ni][r] * iwc[mi][r] * iwy;
                        float d2 = fmaxf(2.f - 2.f * cww, 0.f);
                        part += 1.f / d2;
                    }
                }
            }
        }
        red[t] = part;
        __syncthreads();
        for (int s = 128; s > 0; s >>= 1) {
            if (t < s) red[t] += red[t + s];
            __syncthreads();
        }
        if (t == 0) atomicAdd(inter_sum, red[0]);
    }
}

// ---------------- reduce: merge NMB partials per batch row, CE fixup + argmax ----------------
__global__ __launch_bounds__(64) void reduce_kernel(
    const float4* __restrict__ partials, const float* __restrict__ logits,
    const int* __restrict__ y, const float* __restrict__ mod_val_a,
    float* __restrict__ ce_sum, float* __restrict__ acc_sum)
{
    const int b = blockIdx.x;
    const int t = threadIdx.x;
    float M = -INFINITY, S = 0.f, VM = -INFINITY; int VI = 0x7fffffff;
    for (int i = t; i < NMB; i += 64) {
        float4 p = partials[(size_t)b * NMB + i];
        merge4(M, S, VM, VI, p.x, p.y, p.z, __float_as_int(p.w));
    }
    #pragma unroll
    for (int d = 1; d < 64; d <<= 1) {
        float m2  = __shfl_xor(M, d);
        float s2  = __shfl_xor(S, d);
        float vm2 = __shfl_xor(VM, d);
        int   vi2 = __shfl_xor(VI, d);
        merge4(M, S, VM, VI, m2, s2, vm2, vi2);
    }
    if (t == 0) {
        int   yb  = y[b];
        float vyb = logits[(size_t)b * CLS_N + yb];
        float mv  = mod_val_a[b];
        float m2 = fmaxf(M, mv);
        float s2 = S * __expf(M - m2) - __expf(vyb - m2) + __expf(mv - m2);
        float lse = m2 + logf(s2);
        atomicAdd(ce_sum, -(mv - lse));
        if (VI == yb) atomicAdd(acc_sum, 1.f);
    }
}

__global__ void finalize_kernel(const float* __restrict__ accums, float* __restrict__ out)
{
    float ce    = accums[0] / (float)B_N;
    float acc   = accums[1] / (float)B_N;
    float inter = accums[2] / (float)((double)B_N * (CLS_N - 1));
    out[0] = ce + 0.01f * inter;
    out[(size_t)1 + (size_t)B_N * CLS_N + 0] = acc;
    out[(size_t)1 + (size_t)B_N * CLS_N + 1] = inter;
}

extern "C" void kernel_launch(void* const* d_in, const int* in_sizes, int n_in,
                              void* d_out, int out_size, void* d_ws, size_t ws_size,
                              hipStream_t stream) {
    const float* emb = (const float*)d_in[0];
    const int*   y   = (const int*)d_in[1];
    const float* W   = (const float*)d_in[2];
    float* out = (float*)d_out;
    float* logits = out + 1;   // [loss, logits(256x20000), acc, inter]

    // ws layout (bytes)
    const size_t ABF_OFF  = 0;                                  // 512*512*2 = 524288
    const size_t PART_OFF = 524288;                             // 256*313*16 = 1282048
    const size_t SC_OFF   = PART_OFF + (size_t)B_N * NMB * 16;

    unsigned short* Abf = (unsigned short*)((char*)d_ws + ABF_OFF);
    float4* partials   = (float4*)((char*)d_ws + PART_OFF);
    float*  xlen_a     = (float*)((char*)d_ws + SC_OFF);
    float*  inv_xlen_a = xlen_a + 256;
    float*  inv_wny_a  = xlen_a + 512;
    float*  mod_val_a  = xlen_a + 768;
    float*  accums     = xlen_a + 1024;

    hipMemsetAsync(accums, 0, 3 * sizeof(float), stream);

    prep_kernel<<<B_N, 256, 0, stream>>>(emb, y, W, Abf,
                                         xlen_a, inv_xlen_a, inv_wny_a, mod_val_a);
    mfma_gemm_kernel<<<1280, 256, 0, stream>>>(W, Abf, y,
                                               xlen_a, inv_xlen_a, inv_wny_a,
                                               logits, partials, accums + 2);
    reduce_kernel<<<B_N, 64, 0, stream>>>(partials, logits, y, mod_val_a,
                                          accums + 0, accums + 1);
    finalize_kernel<<<1, 1, 0, stream>>>(accums, out);
}